// Round 26
// baseline (292.211 us; speedup 1.0000x reference)
//
#include <hip/hip_runtime.h>
#include <hip/hip_bf16.h>

typedef unsigned short u16;
typedef __attribute__((ext_vector_type(8))) short bf16x8;
typedef __attribute__((ext_vector_type(4))) float f32x4;
typedef __attribute__((ext_vector_type(2))) unsigned uint2v;

#define MFMA16(a, b, c) __builtin_amdgcn_mfma_f32_16x16x32_bf16(a, b, c, 0, 0, 0)

__device__ __forceinline__ u16 f2bf(float f) {
  union { float f; unsigned u; } v; v.f = f;
  unsigned r = v.u + 0x7fffu + ((v.u >> 16) & 1u);
  return (u16)(r >> 16);
}

// Pack two f32 -> packed bf16 pair (lo in bits 0..15). Pure C++ (no inline asm).
__device__ __forceinline__ unsigned pkbf(float lo, float hi) {
  union { __hip_bfloat162 h; unsigned u; } v;
  v.h = __hip_bfloat162(__float2bfloat16(lo), __float2bfloat16(hi));
  return v.u;
}

// In-register transpose, permlane edition (r14-verified, bit-identical results):
// input a0/a1 = M[t*16+g*4+r][li] (f32, C-layout of a 32x16 block, t=0,1);
// output frag: lane holds bf16 M[g*8+j][li] — MFMA operand fragment for M^T.
__device__ __forceinline__ bf16x8 xform(f32x4 a0, f32x4 a1) {
  unsigned p0 = pkbf(a0[0], a0[1]), p1 = pkbf(a0[2], a0[3]);
  unsigned p2 = pkbf(a1[0], a1[1]), p3 = pkbf(a1[2], a1[3]);
  uint2v s02 = __builtin_amdgcn_permlane32_swap(p0, p2, false, false);
  uint2v w02 = __builtin_amdgcn_permlane16_swap(s02.x, s02.y, false, false);
  uint2v s13 = __builtin_amdgcn_permlane32_swap(p1, p3, false, false);
  uint2v w13 = __builtin_amdgcn_permlane16_swap(s13.x, s13.y, false, false);
  union { bf16x8 v; unsigned w[4]; } o;
  o.w[0] = w02.x; o.w[1] = w13.x; o.w[2] = w02.y; o.w[3] = w13.y;
  return o.v;
}

// xor-16 / xor-32 lane reductions via permlane-swap (VALU; r14-verified).
__device__ __forceinline__ float pmax16(float v) {
  union { float f; unsigned u; } a; a.f = v;
  uint2v r = __builtin_amdgcn_permlane16_swap(a.u, a.u, false, false);
  union { unsigned u; float f; } x, y; x.u = r.x; y.u = r.y;
  return fmaxf(x.f, y.f);
}
__device__ __forceinline__ float pmax32(float v) {
  union { float f; unsigned u; } a; a.f = v;
  uint2v r = __builtin_amdgcn_permlane32_swap(a.u, a.u, false, false);
  union { unsigned u; float f; } x, y; x.u = r.x; y.u = r.y;
  return fmaxf(x.f, y.f);
}
__device__ __forceinline__ float psum16(float v) {
  union { float f; unsigned u; } a; a.f = v;
  uint2v r = __builtin_amdgcn_permlane16_swap(a.u, a.u, false, false);
  union { unsigned u; float f; } x, y; x.u = r.x; y.u = r.y;
  return x.f + y.f;
}
__device__ __forceinline__ float psum32(float v) {
  union { float f; unsigned u; } a; a.f = v;
  uint2v r = __builtin_amdgcn_permlane32_swap(a.u, a.u, false, false);
  union { unsigned u; float f; } x, y; x.u = r.x; y.u = r.y;
  return x.f + y.f;
}

// ---------------- pack: weights -> bf16 fragment layout, bias -> per-lane frag order ----
__global__ void pack_kernel(const float* __restrict__ wqkv_w,
                            const float* __restrict__ wp_w,
                            const float* __restrict__ bias_table,
                            u16* __restrict__ wpack, u16* __restrict__ wppack,
                            float* __restrict__ biasf) {
  int i = blockIdx.x * 256 + threadIdx.x;
  if (i < 110592) {
    int j = i & 7, l = (i >> 3) & 63;
    int rest = i >> 9;
    int ks = rest % 6, nt = rest / 6;
    int k = ks * 32 + (l >> 4) * 8 + j;
    int n = nt * 16 + (l & 15);
    wpack[i] = f2bf(wqkv_w[k * 576 + n]);
  } else if (i < 147456) {
    int i2 = i - 110592;
    int j = i2 & 7, l = (i2 >> 3) & 63;
    int rest = i2 >> 9;
    int ks = rest % 6, nt = rest / 6;
    int k = ks * 32 + (l >> 4) * 8 + j;
    int n = nt * 16 + (l & 15);
    wppack[i2] = f2bf(wp_w[k * 192 + n]);
  } else if (i < 172032) {
    int i2 = i - 147456;            // 0..24575
    int r = i2 & 3, lane = (i2 >> 2) & 63, mt = (i2 >> 8) & 3, nt = (i2 >> 10) & 3, h = i2 >> 12;
    int q = nt * 16 + (lane & 15);
    int kk = mt * 16 + (lane >> 4) * 4 + r;
    int idx = ((q >> 3) - (kk >> 3) + 7) * 15 + ((q & 7) - (kk & 7) + 7);
    biasf[i2] = bias_table[idx * 6 + h];
  }
}

// ---------------- attn: 1 block = 2 WAVES = 2 HEADS of one window (r24 body). ---------
// r26 change vs r25 (single variable): HOISTED WEIGHT LOADS — all 12 QK weight
// fragments batch-loaded before the QK ks-loop, all 12 V fragments before the V
// loop. r25 compiled to VGPR 72 (56 regs unused) and scheduled weight loads
// per-ks, exposing ~6 L2-latency groups per pass; batching converts each pass to
// 1 group hidden under the first MFMAs. Register audit: 48 weights + 16 af +
// accs(AGPR) + ~12 addr ~ 120 arch < 128 cap. TRIPWIRE: WRITE >= 120 MB (spill)
// or dur >= 212 us -> r25 is the final plateau.
__global__ __launch_bounds__(128, 2) void attn6(
    const float* __restrict__ x, const u16* __restrict__ wpack,
    const float* __restrict__ wqkv_b, const float* __restrict__ biasf,
    u16* __restrict__ y) {
  __shared__ u16 xs[12288];                   // [4 mt][6 ks][64 lane][8] bf16
  const int lane = threadIdx.x & 63;
  const int wv = threadIdx.x >> 6;            // 0,1
  // chunked bijective XCD swizzle: 13824 blocks = 8 XCDs x 1728.
  const int fid = (blockIdx.x & 7) * 1728 + (blockIdx.x >> 3);
  const int w = fid / 3, sub = fid - w * 3;   // window, head-pair
  const int h = sub * 2 + wv;                 // this wave's head
  const int bb = w / 576, rem = w - bb * 576;
  const int wy = rem / 24, wx = rem - (rem / 24) * 24;
  const size_t xbase = (size_t)bb * 36864;
  const int g = lane >> 4, li = lane & 15;

  // per-lane pixel for token (mt*16 + li): pix(mt) = pix0 + mt*384
  const int pix0 = (wy * 8 + (li >> 3)) * 192 + wx * 8 + (li & 7);
  const float* xr = x + (xbase + pix0) * 192 + g * 8;
  const u16* wbase = wpack + lane * 8;

  const float scale = 0.17677669529663687f;   // 1/sqrt(32)
  const f32x4 zero4 = {0.f, 0.f, 0.f, 0.f};

  // ---- stage x -> LDS fragments ONCE (2 waves split 24 chunks: 12 each) ----
#pragma unroll
  for (int ci = 0; ci < 12; ++ci) {
    const int c = wv * 12 + ci, mt = c / 6, ks = c - (c / 6) * 6;
    const float* p = xr + mt * 73728 + ks * 32;   // +mt*384 pixels
    float4 f0 = *(const float4*)p;
    float4 f1 = *(const float4*)(p + 4);
    union { bf16x8 v; unsigned u[4]; } o;
    o.u[0] = pkbf(f0.x, f0.y); o.u[1] = pkbf(f0.z, f0.w);
    o.u[2] = pkbf(f1.x, f1.y); o.u[3] = pkbf(f1.z, f1.w);
    *(bf16x8*)(xs + ((mt * 6 + ks) * 64 + lane) * 8) = o.v;
  }
  __syncthreads();

  // ---- pass QK: Q^T, K^T = mfma(W, x_lds), weights pre-hoisted ----
  bf16x8 qf[4], kf[4];
  {
    bf16x8 wqr[6][2], wkr[6][2];
#pragma unroll
    for (int ks = 0; ks < 6; ++ks)
#pragma unroll
      for (int i = 0; i < 2; ++i) {
        wqr[ks][i] = *(const bf16x8*)(wbase + ((2 * h + i) * 6 + ks) * 512);
        wkr[ks][i] = *(const bf16x8*)(wbase + ((12 + 2 * h + i) * 6 + ks) * 512);
      }
    f32x4 qt[2][4], kt[2][4];
#pragma unroll
    for (int i = 0; i < 2; ++i)
#pragma unroll
      for (int mt = 0; mt < 4; ++mt) { qt[i][mt] = zero4; kt[i][mt] = zero4; }
    __builtin_amdgcn_s_setprio(1);
#pragma unroll
    for (int ks = 0; ks < 6; ++ks) {
      bf16x8 af[4];
#pragma unroll
      for (int mt = 0; mt < 4; ++mt)
        af[mt] = *(const bf16x8*)(xs + ((mt * 6 + ks) * 64 + lane) * 8);
#pragma unroll
      for (int i = 0; i < 2; ++i) {
#pragma unroll
        for (int mt = 0; mt < 4; ++mt) {
          qt[i][mt] = MFMA16(wqr[ks][i], af[mt], qt[i][mt]);
          kt[i][mt] = MFMA16(wkr[ks][i], af[mt], kt[i][mt]);
        }
      }
    }
    __builtin_amdgcn_s_setprio(0);
    f32x4 bq0 = *(const f32x4*)(wqkv_b + h * 32 + g * 4);
    f32x4 bq1 = *(const f32x4*)(wqkv_b + h * 32 + 16 + g * 4);
    f32x4 bk0 = *(const f32x4*)(wqkv_b + 192 + h * 32 + g * 4);
    f32x4 bk1 = *(const f32x4*)(wqkv_b + 192 + h * 32 + 16 + g * 4);
#pragma unroll
    for (int mt = 0; mt < 4; ++mt) {
      qf[mt] = xform((qt[0][mt] + bq0) * scale, (qt[1][mt] + bq1) * scale);
      kf[mt] = xform(kt[0][mt] + bk0, kt[1][mt] + bk1);
    }
  }

  // ---- pass V: V = mfma(x_lds, Wv), weights pre-hoisted ----
  bf16x8 vf[2][2];    // [d-tile i][key-chunk ks2] — V^T A-operand
  {
    bf16x8 wvr[6][2];
#pragma unroll
    for (int ks = 0; ks < 6; ++ks) {
      wvr[ks][0] = *(const bf16x8*)(wbase + ((24 + 2 * h) * 6 + ks) * 512);
      wvr[ks][1] = *(const bf16x8*)(wbase + ((25 + 2 * h) * 6 + ks) * 512);
    }
    f32x4 va[4][2];
#pragma unroll
    for (int mt = 0; mt < 4; ++mt) { va[mt][0] = zero4; va[mt][1] = zero4; }
    __builtin_amdgcn_s_setprio(1);
#pragma unroll
    for (int ks = 0; ks < 6; ++ks) {
      bf16x8 af[4];
#pragma unroll
      for (int mt = 0; mt < 4; ++mt)
        af[mt] = *(const bf16x8*)(xs + ((mt * 6 + ks) * 64 + lane) * 8);
#pragma unroll
      for (int mt = 0; mt < 4; ++mt) {
        va[mt][0] = MFMA16(af[mt], wvr[ks][0], va[mt][0]);
        va[mt][1] = MFMA16(af[mt], wvr[ks][1], va[mt][1]);
      }
    }
    __builtin_amdgcn_s_setprio(0);
    float bva0 = wqkv_b[384 + h * 32 + li], bva1 = wqkv_b[384 + h * 32 + 16 + li];
#pragma unroll
    for (int i = 0; i < 2; ++i) {
      float bv = i ? bva1 : bva0;
#pragma unroll
      for (int ks2 = 0; ks2 < 2; ++ks2)
        vf[i][ks2] = xform(va[ks2 * 2][i] + bv, va[ks2 * 2 + 1][i] + bv);
    }
  }

  // ---- per-q-tile: S^T = mfma(K,Q,bias), softmax, P-frag, PV, fused store ----
  const float* bfh = biasf + h * 4096 + lane * 4;
  u16* yp = y + (size_t)h * 9437184 + (xbase + pix0) * 32 + g * 8;
#pragma unroll
  for (int nt = 0; nt < 4; ++nt) {
    f32x4 em[4];
    __builtin_amdgcn_s_setprio(1);
#pragma unroll
    for (int mt = 0; mt < 4; ++mt) {
      f32x4 bias_c = *(const f32x4*)(bfh + (nt * 4 + mt) * 256);
      em[mt] = MFMA16(kf[mt], qf[nt], bias_c);   // bias folded into C-operand
    }
    __builtin_amdgcn_s_setprio(0);
    float mx = -1e30f;
#pragma unroll
    for (int mt = 0; mt < 4; ++mt)
      mx = fmaxf(mx, fmaxf(fmaxf(em[mt][0], em[mt][1]), fmaxf(em[mt][2], em[mt][3])));
    mx = pmax16(mx);
    mx = pmax32(mx);
    float s = 0.f;
#pragma unroll
    for (int mt = 0; mt < 4; ++mt)
#pragma unroll
      for (int r = 0; r < 4; ++r) { em[mt][r] = __expf(em[mt][r] - mx); s += em[mt][r]; }
    s = psum16(s);
    s = psum32(s);
    float inv = 1.0f / s;
    f32x4 y0 = zero4, y1 = zero4;   // this q-tile's output only
    __builtin_amdgcn_s_setprio(1);
#pragma unroll
    for (int ks2 = 0; ks2 < 2; ++ks2) {
      bf16x8 pf = xform(em[ks2 * 2] * inv, em[ks2 * 2 + 1] * inv);
      y0 = MFMA16(vf[0][ks2], pf, y0);
      y1 = MFMA16(vf[1][ks2], pf, y1);
    }
    __builtin_amdgcn_s_setprio(0);
    // Y^T -> y-fragment; store HEAD-MAJOR y'[h][b*36864 + pix][32]
    bf16x8 yfr = xform(y0, y1);
    *(bf16x8*)(yp + nt * 12288) = yfr;   // +nt*384 pixels * 32 ch
  }
}

// ---------------- projection GEMM: out = y' @ wp + b, LDS-staged coalesced stores -----
// r25-verified: osh[64][196] staging (2-way banks, free) + contiguous 2KB-run
// block copy. 128-thread blocks, 64 rows each, grid 4608; 50176 B LDS.
__global__ __launch_bounds__(128, 2) void proj_kernel(
    const u16* __restrict__ y, const u16* __restrict__ wppack,
    const float* __restrict__ wp_b, float* __restrict__ out) {
  __shared__ __align__(16) float osh[64 * 196];
  const int tid = threadIdx.x;
  const int lane = tid & 63, wv = tid >> 6;   // 0,1
  const int g = lane >> 4, li = lane & 15;
  const size_t row0 = (size_t)blockIdx.x * 64 + wv * 32;
  const f32x4 zero4 = {0.f, 0.f, 0.f, 0.f};
  f32x4 acc[2][12];
#pragma unroll
  for (int mt = 0; mt < 2; ++mt)
#pragma unroll
    for (int nt = 0; nt < 12; ++nt) acc[mt][nt] = zero4;
#pragma unroll
  for (int ks = 0; ks < 6; ++ks) {
    bf16x8 af[2];
#pragma unroll
    for (int mt = 0; mt < 2; ++mt)
      af[mt] = *(const bf16x8*)(y + (size_t)ks * 9437184 + (row0 + mt * 16 + li) * 32 + g * 8);
#pragma unroll
    for (int nt = 0; nt < 12; ++nt) {
      bf16x8 bf = *(const bf16x8*)(wppack + (nt * 6 + ks) * 512 + lane * 8);
      acc[0][nt] = MFMA16(af[0], bf, acc[0][nt]);
      acc[1][nt] = MFMA16(af[1], bf, acc[1][nt]);
    }
  }
  // stage to LDS (row-padded 196: g-rows land 16 dwords apart mod 32 -> 2-way, free)
#pragma unroll
  for (int nt = 0; nt < 12; ++nt) {
    float bb = wp_b[nt * 16 + li];
#pragma unroll
    for (int mt = 0; mt < 2; ++mt)
#pragma unroll
      for (int r = 0; r < 4; ++r)
        osh[(wv * 32 + mt * 16 + g * 4 + r) * 196 + nt * 16 + li] = acc[mt][nt][r] + bb;
  }
  __syncthreads();
  // coalesced block copy: 64 rows x 192 floats = 3072 float4, 24 per thread
  const size_t base = (size_t)blockIdx.x * 64 * 192;
#pragma unroll
  for (int i = 0; i < 24; ++i) {
    int idx = i * 128 + tid;
    int row = idx / 48, c4 = idx - row * 48;
    *(float4*)(out + base + row * 192 + c4 * 4) = *(const float4*)(osh + row * 196 + c4 * 4);
  }
}

extern "C" void kernel_launch(void* const* d_in, const int* in_sizes, int n_in,
                              void* d_out, int out_size, void* d_ws, size_t ws_size,
                              hipStream_t stream) {
  (void)in_sizes; (void)n_in; (void)out_size; (void)ws_size;
  const float* x          = (const float*)d_in[0];
  const float* wqkv_w     = (const float*)d_in[1];
  const float* wqkv_b     = (const float*)d_in[2];
  const float* wp_w       = (const float*)d_in[3];
  const float* wp_b       = (const float*)d_in[4];
  const float* bias_table = (const float*)d_in[5];
  float* out = (float*)d_out;
  char* ws = (char*)d_ws;
  u16* wpack   = (u16*)(ws);              // 221184 B
  u16* wppack  = (u16*)(ws + 221184);     //  73728 B
  float* biasf = (float*)(ws + 294912);   //  98304 B
  u16* y       = (u16*)(ws + 393216);     // 113246208 B (head-major: [6][294912][32])

  pack_kernel<<<672, 256, 0, stream>>>(wqkv_w, wp_w, bias_table, wpack, wppack, biasf);
  attn6<<<13824, 128, 0, stream>>>(x, wpack, wqkv_b, biasf, y);
  proj_kernel<<<4608, 128, 0, stream>>>(y, wppack, wp_b, out);
}

// Round 27
// 289.263 us; speedup vs baseline: 1.0102x; 1.0102x over previous
//
#include <hip/hip_runtime.h>
#include <hip/hip_bf16.h>

typedef unsigned short u16;
typedef __attribute__((ext_vector_type(8))) short bf16x8;
typedef __attribute__((ext_vector_type(4))) float f32x4;
typedef __attribute__((ext_vector_type(2))) unsigned uint2v;

#define MFMA16(a, b, c) __builtin_amdgcn_mfma_f32_16x16x32_bf16(a, b, c, 0, 0, 0)

__device__ __forceinline__ u16 f2bf(float f) {
  union { float f; unsigned u; } v; v.f = f;
  unsigned r = v.u + 0x7fffu + ((v.u >> 16) & 1u);
  return (u16)(r >> 16);
}

// Pack two f32 -> packed bf16 pair (lo in bits 0..15). Pure C++ (no inline asm).
__device__ __forceinline__ unsigned pkbf(float lo, float hi) {
  union { __hip_bfloat162 h; unsigned u; } v;
  v.h = __hip_bfloat162(__float2bfloat16(lo), __float2bfloat16(hi));
  return v.u;
}

// In-register transpose, permlane edition (r14-verified, bit-identical results):
// input a0/a1 = M[t*16+g*4+r][li] (f32, C-layout of a 32x16 block, t=0,1);
// output frag: lane holds bf16 M[g*8+j][li] — MFMA operand fragment for M^T.
__device__ __forceinline__ bf16x8 xform(f32x4 a0, f32x4 a1) {
  unsigned p0 = pkbf(a0[0], a0[1]), p1 = pkbf(a0[2], a0[3]);
  unsigned p2 = pkbf(a1[0], a1[1]), p3 = pkbf(a1[2], a1[3]);
  uint2v s02 = __builtin_amdgcn_permlane32_swap(p0, p2, false, false);
  uint2v w02 = __builtin_amdgcn_permlane16_swap(s02.x, s02.y, false, false);
  uint2v s13 = __builtin_amdgcn_permlane32_swap(p1, p3, false, false);
  uint2v w13 = __builtin_amdgcn_permlane16_swap(s13.x, s13.y, false, false);
  union { bf16x8 v; unsigned w[4]; } o;
  o.w[0] = w02.x; o.w[1] = w13.x; o.w[2] = w02.y; o.w[3] = w13.y;
  return o.v;
}

// xor-16 / xor-32 lane reductions via permlane-swap (VALU; r14-verified).
__device__ __forceinline__ float pmax16(float v) {
  union { float f; unsigned u; } a; a.f = v;
  uint2v r = __builtin_amdgcn_permlane16_swap(a.u, a.u, false, false);
  union { unsigned u; float f; } x, y; x.u = r.x; y.u = r.y;
  return fmaxf(x.f, y.f);
}
__device__ __forceinline__ float pmax32(float v) {
  union { float f; unsigned u; } a; a.f = v;
  uint2v r = __builtin_amdgcn_permlane32_swap(a.u, a.u, false, false);
  union { unsigned u; float f; } x, y; x.u = r.x; y.u = r.y;
  return fmaxf(x.f, y.f);
}
__device__ __forceinline__ float psum16(float v) {
  union { float f; unsigned u; } a; a.f = v;
  uint2v r = __builtin_amdgcn_permlane16_swap(a.u, a.u, false, false);
  union { unsigned u; float f; } x, y; x.u = r.x; y.u = r.y;
  return x.f + y.f;
}
__device__ __forceinline__ float psum32(float v) {
  union { float f; unsigned u; } a; a.f = v;
  uint2v r = __builtin_amdgcn_permlane32_swap(a.u, a.u, false, false);
  union { unsigned u; float f; } x, y; x.u = r.x; y.u = r.y;
  return x.f + y.f;
}

// ---------------- pack: weights -> bf16 fragment layout, bias -> per-lane frag order ----
__global__ void pack_kernel(const float* __restrict__ wqkv_w,
                            const float* __restrict__ wp_w,
                            const float* __restrict__ bias_table,
                            u16* __restrict__ wpack, u16* __restrict__ wppack,
                            float* __restrict__ biasf) {
  int i = blockIdx.x * 256 + threadIdx.x;
  if (i < 110592) {
    int j = i & 7, l = (i >> 3) & 63;
    int rest = i >> 9;
    int ks = rest % 6, nt = rest / 6;
    int k = ks * 32 + (l >> 4) * 8 + j;
    int n = nt * 16 + (l & 15);
    wpack[i] = f2bf(wqkv_w[k * 576 + n]);
  } else if (i < 147456) {
    int i2 = i - 110592;
    int j = i2 & 7, l = (i2 >> 3) & 63;
    int rest = i2 >> 9;
    int ks = rest % 6, nt = rest / 6;
    int k = ks * 32 + (l >> 4) * 8 + j;
    int n = nt * 16 + (l & 15);
    wppack[i2] = f2bf(wp_w[k * 192 + n]);
  } else if (i < 172032) {
    int i2 = i - 147456;            // 0..24575
    int r = i2 & 3, lane = (i2 >> 2) & 63, mt = (i2 >> 8) & 3, nt = (i2 >> 10) & 3, h = i2 >> 12;
    int q = nt * 16 + (lane & 15);
    int kk = mt * 16 + (lane >> 4) * 4 + r;
    int idx = ((q >> 3) - (kk >> 3) + 7) * 15 + ((q & 7) - (kk & 7) + 7);
    biasf[i2] = bias_table[idx * 6 + h];
  }
}

// ---------------- attn: 1 block = 2 WAVES = 2 HEADS of one window (r24/r25 FINAL). ----
// Final configuration (best measured: attn ~210 us, VGPR 72, FETCH/WRITE exactly
// ideal, 0 conflicts, occupancy ~32%). Trade-space exhaustively mapped over
// r14-r26: 3 waves/SIMD spills (r21); 1-pass churns AGPRs (r22); weight hoisting
// neutral (r26); setprio +2us (r23); permlane cross-lane (r14); head-major y
// (r12); merged-QK 2-pass (r24). Latency-bound at the 2-wave/SIMD register
// ceiling — the structure's floor. FROZEN.
__global__ __launch_bounds__(128, 2) void attn6(
    const float* __restrict__ x, const u16* __restrict__ wpack,
    const float* __restrict__ wqkv_b, const float* __restrict__ biasf,
    u16* __restrict__ y) {
  __shared__ u16 xs[12288];                   // [4 mt][6 ks][64 lane][8] bf16
  const int lane = threadIdx.x & 63;
  const int wv = threadIdx.x >> 6;            // 0,1
  // chunked bijective XCD swizzle: 13824 blocks = 8 XCDs x 1728.
  const int fid = (blockIdx.x & 7) * 1728 + (blockIdx.x >> 3);
  const int w = fid / 3, sub = fid - w * 3;   // window, head-pair
  const int h = sub * 2 + wv;                 // this wave's head
  const int bb = w / 576, rem = w - bb * 576;
  const int wy = rem / 24, wx = rem - (rem / 24) * 24;
  const size_t xbase = (size_t)bb * 36864;
  const int g = lane >> 4, li = lane & 15;

  // per-lane pixel for token (mt*16 + li): pix(mt) = pix0 + mt*384
  const int pix0 = (wy * 8 + (li >> 3)) * 192 + wx * 8 + (li & 7);
  const float* xr = x + (xbase + pix0) * 192 + g * 8;
  const u16* wbase = wpack + lane * 8;

  const float scale = 0.17677669529663687f;   // 1/sqrt(32)
  const f32x4 zero4 = {0.f, 0.f, 0.f, 0.f};

  // ---- stage x -> LDS fragments ONCE (2 waves split 24 chunks: 12 each) ----
#pragma unroll
  for (int ci = 0; ci < 12; ++ci) {
    const int c = wv * 12 + ci, mt = c / 6, ks = c - (c / 6) * 6;
    const float* p = xr + mt * 73728 + ks * 32;   // +mt*384 pixels
    float4 f0 = *(const float4*)p;
    float4 f1 = *(const float4*)(p + 4);
    union { bf16x8 v; unsigned u[4]; } o;
    o.u[0] = pkbf(f0.x, f0.y); o.u[1] = pkbf(f0.z, f0.w);
    o.u[2] = pkbf(f1.x, f1.y); o.u[3] = pkbf(f1.z, f1.w);
    *(bf16x8*)(xs + ((mt * 6 + ks) * 64 + lane) * 8) = o.v;
  }
  __syncthreads();

  // ---- pass QK: Q^T, K^T = mfma(W, x_lds)  (64-reg accumulator block) ----
  bf16x8 qf[4], kf[4];
  {
    f32x4 qt[2][4], kt[2][4];
#pragma unroll
    for (int i = 0; i < 2; ++i)
#pragma unroll
      for (int mt = 0; mt < 4; ++mt) { qt[i][mt] = zero4; kt[i][mt] = zero4; }
    __builtin_amdgcn_s_setprio(1);
#pragma unroll
    for (int ks = 0; ks < 6; ++ks) {
      bf16x8 af[4];
#pragma unroll
      for (int mt = 0; mt < 4; ++mt)
        af[mt] = *(const bf16x8*)(xs + ((mt * 6 + ks) * 64 + lane) * 8);
#pragma unroll
      for (int i = 0; i < 2; ++i) {
        bf16x8 wq = *(const bf16x8*)(wbase + ((2 * h + i) * 6 + ks) * 512);
        bf16x8 wk = *(const bf16x8*)(wbase + ((12 + 2 * h + i) * 6 + ks) * 512);
#pragma unroll
        for (int mt = 0; mt < 4; ++mt) {
          qt[i][mt] = MFMA16(wq, af[mt], qt[i][mt]);
          kt[i][mt] = MFMA16(wk, af[mt], kt[i][mt]);
        }
      }
    }
    __builtin_amdgcn_s_setprio(0);
    f32x4 bq0 = *(const f32x4*)(wqkv_b + h * 32 + g * 4);
    f32x4 bq1 = *(const f32x4*)(wqkv_b + h * 32 + 16 + g * 4);
    f32x4 bk0 = *(const f32x4*)(wqkv_b + 192 + h * 32 + g * 4);
    f32x4 bk1 = *(const f32x4*)(wqkv_b + 192 + h * 32 + 16 + g * 4);
#pragma unroll
    for (int mt = 0; mt < 4; ++mt) {
      qf[mt] = xform((qt[0][mt] + bq0) * scale, (qt[1][mt] + bq1) * scale);
      kf[mt] = xform(kt[0][mt] + bk0, kt[1][mt] + bk1);
    }
  }

  // ---- pass V: V = mfma(x_lds, Wv)  (32-reg accumulator block) ----
  bf16x8 vf[2][2];    // [d-tile i][key-chunk ks2] — V^T A-operand
  {
    f32x4 va[4][2];
#pragma unroll
    for (int mt = 0; mt < 4; ++mt) { va[mt][0] = zero4; va[mt][1] = zero4; }
    __builtin_amdgcn_s_setprio(1);
#pragma unroll
    for (int ks = 0; ks < 6; ++ks) {
      bf16x8 af[4];
#pragma unroll
      for (int mt = 0; mt < 4; ++mt)
        af[mt] = *(const bf16x8*)(xs + ((mt * 6 + ks) * 64 + lane) * 8);
      bf16x8 wv0 = *(const bf16x8*)(wbase + ((24 + 2 * h) * 6 + ks) * 512);
      bf16x8 wv1 = *(const bf16x8*)(wbase + ((25 + 2 * h) * 6 + ks) * 512);
#pragma unroll
      for (int mt = 0; mt < 4; ++mt) {
        va[mt][0] = MFMA16(af[mt], wv0, va[mt][0]);
        va[mt][1] = MFMA16(af[mt], wv1, va[mt][1]);
      }
    }
    __builtin_amdgcn_s_setprio(0);
    float bva0 = wqkv_b[384 + h * 32 + li], bva1 = wqkv_b[384 + h * 32 + 16 + li];
#pragma unroll
    for (int i = 0; i < 2; ++i) {
      float bv = i ? bva1 : bva0;
#pragma unroll
      for (int ks2 = 0; ks2 < 2; ++ks2)
        vf[i][ks2] = xform(va[ks2 * 2][i] + bv, va[ks2 * 2 + 1][i] + bv);
    }
  }

  // ---- per-q-tile: S^T = mfma(K,Q,bias), softmax, P-frag, PV, fused store ----
  const float* bfh = biasf + h * 4096 + lane * 4;
  u16* yp = y + (size_t)h * 9437184 + (xbase + pix0) * 32 + g * 8;
#pragma unroll
  for (int nt = 0; nt < 4; ++nt) {
    f32x4 em[4];
    __builtin_amdgcn_s_setprio(1);
#pragma unroll
    for (int mt = 0; mt < 4; ++mt) {
      f32x4 bias_c = *(const f32x4*)(bfh + (nt * 4 + mt) * 256);
      em[mt] = MFMA16(kf[mt], qf[nt], bias_c);   // bias folded into C-operand
    }
    __builtin_amdgcn_s_setprio(0);
    float mx = -1e30f;
#pragma unroll
    for (int mt = 0; mt < 4; ++mt)
      mx = fmaxf(mx, fmaxf(fmaxf(em[mt][0], em[mt][1]), fmaxf(em[mt][2], em[mt][3])));
    mx = pmax16(mx);
    mx = pmax32(mx);
    float s = 0.f;
#pragma unroll
    for (int mt = 0; mt < 4; ++mt)
#pragma unroll
      for (int r = 0; r < 4; ++r) { em[mt][r] = __expf(em[mt][r] - mx); s += em[mt][r]; }
    s = psum16(s);
    s = psum32(s);
    float inv = 1.0f / s;
    f32x4 y0 = zero4, y1 = zero4;   // this q-tile's output only
    __builtin_amdgcn_s_setprio(1);
#pragma unroll
    for (int ks2 = 0; ks2 < 2; ++ks2) {
      bf16x8 pf = xform(em[ks2 * 2] * inv, em[ks2 * 2 + 1] * inv);
      y0 = MFMA16(vf[0][ks2], pf, y0);
      y1 = MFMA16(vf[1][ks2], pf, y1);
    }
    __builtin_amdgcn_s_setprio(0);
    // Y^T -> y-fragment; store HEAD-MAJOR y'[h][b*36864 + pix][32]
    bf16x8 yfr = xform(y0, y1);
    *(bf16x8*)(yp + nt * 12288) = yfr;   // +nt*384 pixels * 32 ch
  }
}

// ---------------- projection GEMM: out = y' @ wp + b, LDS-staged coalesced stores -----
// r25-verified: osh[64][196] staging (2-way banks, free) + contiguous 2KB-run
// block copy. 128-thread blocks, 64 rows each, grid 4608; 50176 B LDS.
__global__ __launch_bounds__(128, 2) void proj_kernel(
    const u16* __restrict__ y, const u16* __restrict__ wppack,
    const float* __restrict__ wp_b, float* __restrict__ out) {
  __shared__ __align__(16) float osh[64 * 196];
  const int tid = threadIdx.x;
  const int lane = tid & 63, wv = tid >> 6;   // 0,1
  const int g = lane >> 4, li = lane & 15;
  const size_t row0 = (size_t)blockIdx.x * 64 + wv * 32;
  const f32x4 zero4 = {0.f, 0.f, 0.f, 0.f};
  f32x4 acc[2][12];
#pragma unroll
  for (int mt = 0; mt < 2; ++mt)
#pragma unroll
    for (int nt = 0; nt < 12; ++nt) acc[mt][nt] = zero4;
#pragma unroll
  for (int ks = 0; ks < 6; ++ks) {
    bf16x8 af[2];
#pragma unroll
    for (int mt = 0; mt < 2; ++mt)
      af[mt] = *(const bf16x8*)(y + (size_t)ks * 9437184 + (row0 + mt * 16 + li) * 32 + g * 8);
#pragma unroll
    for (int nt = 0; nt < 12; ++nt) {
      bf16x8 bf = *(const bf16x8*)(wppack + (nt * 6 + ks) * 512 + lane * 8);
      acc[0][nt] = MFMA16(af[0], bf, acc[0][nt]);
      acc[1][nt] = MFMA16(af[1], bf, acc[1][nt]);
    }
  }
  // stage to LDS (row-padded 196: g-rows land 16 dwords apart mod 32 -> 2-way, free)
#pragma unroll
  for (int nt = 0; nt < 12; ++nt) {
    float bb = wp_b[nt * 16 + li];
#pragma unroll
    for (int mt = 0; mt < 2; ++mt)
#pragma unroll
      for (int r = 0; r < 4; ++r)
        osh[(wv * 32 + mt * 16 + g * 4 + r) * 196 + nt * 16 + li] = acc[mt][nt][r] + bb;
  }
  __syncthreads();
  // coalesced block copy: 64 rows x 192 floats = 3072 float4, 24 per thread
  const size_t base = (size_t)blockIdx.x * 64 * 192;
#pragma unroll
  for (int i = 0; i < 24; ++i) {
    int idx = i * 128 + tid;
    int row = idx / 48, c4 = idx - row * 48;
    *(float4*)(out + base + row * 192 + c4 * 4) = *(const float4*)(osh + row * 196 + c4 * 4);
  }
}

extern "C" void kernel_launch(void* const* d_in, const int* in_sizes, int n_in,
                              void* d_out, int out_size, void* d_ws, size_t ws_size,
                              hipStream_t stream) {
  (void)in_sizes; (void)n_in; (void)out_size; (void)ws_size;
  const float* x          = (const float*)d_in[0];
  const float* wqkv_w     = (const float*)d_in[1];
  const float* wqkv_b     = (const float*)d_in[2];
  const float* wp_w       = (const float*)d_in[3];
  const float* wp_b       = (const float*)d_in[4];
  const float* bias_table = (const float*)d_in[5];
  float* out = (float*)d_out;
  char* ws = (char*)d_ws;
  u16* wpack   = (u16*)(ws);              // 221184 B
  u16* wppack  = (u16*)(ws + 221184);     //  73728 B
  float* biasf = (float*)(ws + 294912);   //  98304 B
  u16* y       = (u16*)(ws + 393216);     // 113246208 B (head-major: [6][294912][32])

  pack_kernel<<<672, 256, 0, stream>>>(wqkv_w, wp_w, bias_table, wpack, wppack, biasf);
  attn6<<<13824, 128, 0, stream>>>(x, wpack, wqkv_b, biasf, y);
  proj_kernel<<<4608, 128, 0, stream>>>(y, wppack, wp_b, out);
}